// Round 5
// baseline (18959.607 us; speedup 1.0000x reference)
//
#include <hip/hip_runtime.h>

typedef unsigned int uint;
typedef unsigned long long u64;
typedef __attribute__((ext_vector_type(4))) float f32x4;
typedef __attribute__((ext_vector_type(8))) short s16x8;   // 8 bf16 in 4 VGPRs

union U4 { uint u[4]; s16x8 v; uint4 q; };

#define TT 4096
#define HC2 512
#define SENT 0xFFFFFFFFu
#define WAVES_PER_LAYER 32u   // 8 blocks x 4 waves publish each step

// ---------- helpers ----------
__device__ __forceinline__ uint bf16_rne(float f) {
  uint x = __float_as_uint(f);
  x += 0x7fffu + ((x >> 16) & 1u);
  return x >> 16;
}
// split f into hi(bf16, low 16 bits) + lo(bf16 of remainder, high 16 bits)
// NOTE: hi is bf16 of a finite tanh/input value -> never 0xFFFF (NaN pattern),
// so a packed word can never equal SENT. Float tanh output can likewise never
// be 0xFFFFFFFF (that is a NaN). This is the backstop sentinel's safety.
__device__ __forceinline__ uint pack_split(float f) {
  uint hi = bf16_rne(f);
  float fh = __uint_as_float(hi << 16);
  uint lo = bf16_rne(f - fh);
  return hi | (lo << 16);
}
__device__ __forceinline__ float fast_tanh(float y) {
  float e = __builtin_amdgcn_exp2f(y * 2.885390081777927f);
  return 1.0f - 2.0f * __builtin_amdgcn_rcpf(e + 1.0f);
}

// system-scope (sc0 sc1): straight to the die-level coherent point. The ONLY
// empirically-validated intra-kernel cross-CU path on this part (R2's
// XCD-pinned sc0/L2 variant regressed 66% -> reverted).
__device__ __forceinline__ void st_sys(uint* p, uint v) {
  asm volatile("global_store_dword %0, %1, off sc0 sc1" :: "v"(p), "v"(v) : "memory");
}
// single-word system-scope load (flag polls: all lanes same address -> 1 line)
__device__ __forceinline__ uint ld1_sys(const uint* p) {
  uint w;
  asm volatile("global_load_dword %0, %1, off sc0 sc1\n\t"
               "s_waitcnt vmcnt(0)" : "=&v"(w) : "v"(p) : "memory");
  return w;
}
__device__ __forceinline__ void ld16_sys(const uint* p, uint4& a, uint4& b, uint4& c, uint4& d) {
  asm volatile("global_load_dwordx4 %0, %4, off sc0 sc1\n\t"
               "global_load_dwordx4 %1, %4, off offset:16 sc0 sc1\n\t"
               "global_load_dwordx4 %2, %4, off offset:32 sc0 sc1\n\t"
               "global_load_dwordx4 %3, %4, off offset:48 sc0 sc1\n\t"
               "s_waitcnt vmcnt(0)"
               : "=&v"(a), "=&v"(b), "=&v"(c), "=&v"(d) : "v"(p) : "memory");
}
__device__ __forceinline__ void ld32_sys(const uint* pa, const uint* pb,
                                         uint4& a, uint4& b, uint4& c, uint4& d,
                                         uint4& e, uint4& f, uint4& g, uint4& h) {
  asm volatile("global_load_dwordx4 %0, %8, off sc0 sc1\n\t"
               "global_load_dwordx4 %1, %8, off offset:16 sc0 sc1\n\t"
               "global_load_dwordx4 %2, %8, off offset:32 sc0 sc1\n\t"
               "global_load_dwordx4 %3, %8, off offset:48 sc0 sc1\n\t"
               "global_load_dwordx4 %4, %9, off sc0 sc1\n\t"
               "global_load_dwordx4 %5, %9, off offset:16 sc0 sc1\n\t"
               "global_load_dwordx4 %6, %9, off offset:32 sc0 sc1\n\t"
               "global_load_dwordx4 %7, %9, off offset:48 sc0 sc1\n\t"
               "s_waitcnt vmcnt(0)"
               : "=&v"(a), "=&v"(b), "=&v"(c), "=&v"(d),
                 "=&v"(e), "=&v"(f), "=&v"(g), "=&v"(h)
               : "v"(pa), "v"(pb) : "memory");
}
// release fence: wait until this wave's prior sc1 stores are ACKed at the
// coherent point, so a subsequent atomic increment can act as the ready token.
__device__ __forceinline__ void release_fence() {
  asm volatile("s_waitcnt vmcnt(0)" ::: "memory");
}

// ---------- pack weights: M[k][j] stored transposed+split as MT[j][k] (uint32) ----------
__global__ void pack_weights_kernel(const float* __restrict__ wr, const float* __restrict__ wi,
                                    const float* __restrict__ wbr, const float* __restrict__ wbi,
                                    const float* __restrict__ ur, const float* __restrict__ ui,
                                    const float* __restrict__ ubr, const float* __restrict__ ubi,
                                    uint* __restrict__ MwT, uint* __restrict__ MuT,
                                    float* __restrict__ bias) {
  const int id = blockIdx.x * 256 + threadIdx.x;   // 0..262143
  const int j = id >> 9, k = id & 511;
  const int jj = j & 255, kk = k & 255;
  float mw, mu;
  if (k < 256) {
    if (j < 256) { mw =  wr[kk * 256 + jj]; mu =  ur[kk * 256 + jj]; }
    else         { mw =  wi[kk * 256 + jj]; mu =  ui[kk * 256 + jj]; }
  } else {
    if (j < 256) { mw = -wi[kk * 256 + jj]; mu = -ui[kk * 256 + jj]; }
    else         { mw =  wr[kk * 256 + jj]; mu =  ur[kk * 256 + jj]; }
  }
  MwT[id] = pack_split(mw);
  MuT[id] = pack_split(mu);
  if (id < 512)
    bias[id] = (id < 256) ? (wbr[id] + ubr[id]) : (wbi[id - 256] + ubi[id - 256]);
}

// ---------- pack x (fp32 -> split uint32) ----------
__global__ void pack_x_kernel(const float* __restrict__ x, uint* __restrict__ xp) {
  const u64 i = ((u64)blockIdx.x * 256 + threadIdx.x) * 4;
  float4 v = *(const float4*)(x + i);
  uint4 o;
  o.x = pack_split(v.x); o.y = pack_split(v.y);
  o.z = pack_split(v.z); o.w = pack_split(v.w);
  *(uint4*)(xp + i) = o;
}

// ---------- split-bf16 MFMA GEMM:  C[32768][512] = A[32768][512] * B[512][512] + bias ----------
__global__ __launch_bounds__(256, 2)
void gemm_split_kernel(const uint* __restrict__ A, const uint* __restrict__ BT,
                       const float* __restrict__ bias, float* __restrict__ C) {
  __shared__ __align__(16) uint a_s[128][36];
  __shared__ __align__(16) uint b_s[128][36];
  const int tid = threadIdx.x;
  const int wv = tid >> 6, lane = tid & 63;
  const int q = lane >> 4, cl = lane & 15;
  const int row0 = (int)blockIdx.x * 128, col0 = (int)blockIdx.y * 128;
  const int wro = (wv >> 1) * 64, wco = (wv & 1) * 64;
  const int sr = tid >> 1, sc = (tid & 1) * 16;

  f32x4 acc[4][4];
#pragma unroll
  for (int a = 0; a < 4; ++a)
#pragma unroll
    for (int b = 0; b < 4; ++b) acc[a][b] = (f32x4){0.f, 0.f, 0.f, 0.f};

  const uint* ga = A + (u64)(row0 + sr) * 512 + sc;
  const uint* gb = BT + (u64)(col0 + sr) * 512 + sc;

  for (int kb = 0; kb < 16; ++kb) {
    uint4 va0 = *(const uint4*)(ga + 0), va1 = *(const uint4*)(ga + 4);
    uint4 va2 = *(const uint4*)(ga + 8), va3 = *(const uint4*)(ga + 12);
    uint4 vb0 = *(const uint4*)(gb + 0), vb1 = *(const uint4*)(gb + 4);
    uint4 vb2 = *(const uint4*)(gb + 8), vb3 = *(const uint4*)(gb + 12);
    ga += 32; gb += 32;
    __syncthreads();
    *(uint4*)&a_s[sr][sc + 0] = va0;  *(uint4*)&a_s[sr][sc + 4] = va1;
    *(uint4*)&a_s[sr][sc + 8] = va2;  *(uint4*)&a_s[sr][sc + 12] = va3;
    *(uint4*)&b_s[sr][sc + 0] = vb0;  *(uint4*)&b_s[sr][sc + 4] = vb1;
    *(uint4*)&b_s[sr][sc + 8] = vb2;  *(uint4*)&b_s[sr][sc + 12] = vb3;
    __syncthreads();

    s16x8 ah[4], al[4];
#pragma unroll
    for (int rt = 0; rt < 4; ++rt) {
      const uint* p = &a_s[wro + rt * 16 + cl][q * 8];
      uint4 p0 = *(const uint4*)(p), p1 = *(const uint4*)(p + 4);
      U4 th, tl;
      th.u[0] = (p0.x & 0xffffu) | (p0.y << 16);
      th.u[1] = (p0.z & 0xffffu) | (p0.w << 16);
      th.u[2] = (p1.x & 0xffffu) | (p1.y << 16);
      th.u[3] = (p1.z & 0xffffu) | (p1.w << 16);
      tl.u[0] = (p0.x >> 16) | (p0.y & 0xffff0000u);
      tl.u[1] = (p0.z >> 16) | (p0.w & 0xffff0000u);
      tl.u[2] = (p1.x >> 16) | (p1.y & 0xffff0000u);
      tl.u[3] = (p1.z >> 16) | (p1.w & 0xffff0000u);
      ah[rt] = th.v; al[rt] = tl.v;
    }
#pragma unroll
    for (int ct = 0; ct < 4; ++ct) {
      const uint* p = &b_s[wco + ct * 16 + cl][q * 8];
      uint4 p0 = *(const uint4*)(p), p1 = *(const uint4*)(p + 4);
      U4 th, tl;
      th.u[0] = (p0.x & 0xffffu) | (p0.y << 16);
      th.u[1] = (p0.z & 0xffffu) | (p0.w << 16);
      th.u[2] = (p1.x & 0xffffu) | (p1.y << 16);
      th.u[3] = (p1.z & 0xffffu) | (p1.w << 16);
      tl.u[0] = (p0.x >> 16) | (p0.y & 0xffff0000u);
      tl.u[1] = (p0.z >> 16) | (p0.w & 0xffff0000u);
      tl.u[2] = (p1.x >> 16) | (p1.y & 0xffff0000u);
      tl.u[3] = (p1.z >> 16) | (p1.w & 0xffff0000u);
#pragma unroll
      for (int rt = 0; rt < 4; ++rt) {
        acc[rt][ct] = __builtin_amdgcn_mfma_f32_16x16x32_bf16(ah[rt], th.v, acc[rt][ct], 0, 0, 0);
        acc[rt][ct] = __builtin_amdgcn_mfma_f32_16x16x32_bf16(al[rt], th.v, acc[rt][ct], 0, 0, 0);
        acc[rt][ct] = __builtin_amdgcn_mfma_f32_16x16x32_bf16(ah[rt], tl.v, acc[rt][ct], 0, 0, 0);
      }
    }
  }
#pragma unroll
  for (int ct = 0; ct < 4; ++ct) {
    const int col = col0 + wco + ct * 16 + cl;
    const float bv = bias[col];
#pragma unroll
    for (int rt = 0; rt < 4; ++rt) {
      const int rbase = row0 + wro + rt * 16 + q * 4;
#pragma unroll
      for (int r2 = 0; r2 < 4; ++r2)
        C[(u64)(rbase + r2) * 512 + col] = acc[rt][ct][r2] + bv;
    }
  }
}

// ---------- fused pipelined scan: 16 persistent blocks ----------
// blocks 0..7  : layer-0 scan. Exchange = packed h0 in xpk0.
// blocks 8..15 : layer-1 scan, pipelined one step behind layer 0:
//                y = W1*h0(t) + U1*h1(t-1) + bias1.  Exchange = FLOAT h1
//                stored straight into d_out (doubles as output).
// R5: FLAG protocol. Each wave, after its step-t st_sys publishes, executes a
// release fence (s_waitcnt vmcnt(0): stores ACKed at the coherent point) and
// lane 0 fire-and-forget atomicAdd's flag[layer][t]. Consumers spin on that
// ONE word (all lanes same address -> 1 line/iter, vs 64 lines for data
// polling — this was R4's flaw: FETCH_SIZE stayed at 833 MB because a
// per-lane "light" poll still touched 64 distinct lines). When the counter
// hits 32 (8 blocks x 4 waves) the data is loaded ONCE. The R1-proven
// sentinel verify (exchange pre-poisoned 0xFF) is kept as a zero-cost
// backstop: it passes first try when the release idiom holds, and retries
// (bounded) if it ever doesn't. All spins bounded + sticky wave-uniform
// timeout -> no hang; worst case fast-fail with wrong output.
__global__ __launch_bounds__(256, 1)
void fused_scan_kernel(const uint* __restrict__ MuT0, const float* __restrict__ wxb,
                       const uint* __restrict__ MwT1, const uint* __restrict__ MuT1,
                       const float* __restrict__ bias1,
                       uint* __restrict__ xpk0,     // packed h0 exchange (64 MB)
                       uint* __restrict__ h1x,      // d_out as uint: float h1 exchange + output
                       uint* __restrict__ flag0,    // [TT] step-ready counters, layer 0
                       uint* __restrict__ flag1) {  // [TT] step-ready counters, layer 1
  __shared__ __align__(16) unsigned short xah[16][520];  // recurrent-h hi plane
  __shared__ __align__(16) unsigned short xal[16][520];  // recurrent-h lo plane
  __shared__ __align__(16) unsigned short yah[16][520];  // (L1 only) h0 hi plane
  __shared__ __align__(16) unsigned short yal[16][520];  // (L1 only) h0 lo plane
  const int tid = threadIdx.x;
  const int wv = tid >> 6, lane = tid & 63;
  const int q = lane >> 4, cl = lane & 15;
  const int layer = (int)blockIdx.x >> 3;
  const int blk = (int)blockIdx.x & 7;
  const int j = blk * 64 + wv * 16 + cl;           // this lane's output column

  for (int idx = tid; idx < 16 * 520; idx += 256) {
    ((unsigned short*)xah)[idx] = 0; ((unsigned short*)xal)[idx] = 0;
    ((unsigned short*)yah)[idx] = 0; ((unsigned short*)yal)[idx] = 0;
  }

  // recurrent weights -> registers (B-operand frags: col=lane&15, k=q*8+e)
  uint4 bh4[16], bl4[16];
  {
    const uint* urow = (layer ? MuT1 : MuT0) + (u64)j * 512;
#pragma unroll
    for (int ks = 0; ks < 16; ++ks) {
      const int k0 = ks * 32 + q * 8;
      uint4 p0 = *(const uint4*)(urow + k0);
      uint4 p1 = *(const uint4*)(urow + k0 + 4);
      uint4 h, l;
      h.x = (p0.x & 0xffffu) | (p0.y << 16);
      h.y = (p0.z & 0xffffu) | (p0.w << 16);
      h.z = (p1.x & 0xffffu) | (p1.y << 16);
      h.w = (p1.z & 0xffffu) | (p1.w << 16);
      l.x = (p0.x >> 16) | (p0.y & 0xffff0000u);
      l.y = (p0.z >> 16) | (p0.w & 0xffff0000u);
      l.z = (p1.x >> 16) | (p1.y & 0xffff0000u);
      l.w = (p1.z >> 16) | (p1.w & 0xffff0000u);
      bh4[ks] = h; bl4[ks] = l;
    }
  }
  // layer-1 input-projection weights -> registers (same fragment layout)
  uint4 ch4[16], cl4[16];
  if (layer) {
    const uint* wrow = MwT1 + (u64)j * 512;
#pragma unroll
    for (int ks = 0; ks < 16; ++ks) {
      const int k0 = ks * 32 + q * 8;
      uint4 p0 = *(const uint4*)(wrow + k0);
      uint4 p1 = *(const uint4*)(wrow + k0 + 4);
      uint4 h, l;
      h.x = (p0.x & 0xffffu) | (p0.y << 16);
      h.y = (p0.z & 0xffffu) | (p0.w << 16);
      h.z = (p1.x & 0xffffu) | (p1.y << 16);
      h.w = (p1.z & 0xffffu) | (p1.w << 16);
      l.x = (p0.x >> 16) | (p0.y & 0xffff0000u);
      l.y = (p0.z >> 16) | (p0.w & 0xffff0000u);
      l.z = (p1.x >> 16) | (p1.y & 0xffff0000u);
      l.w = (p1.z >> 16) | (p1.w & 0xffff0000u);
      ch4[ks] = h; cl4[ks] = l;
    }
  }
  __syncthreads();

  const int srow = tid >> 5;            // staging: 32 threads per batch row
  const int scol = (tid & 31) * 16;
  bool timeout = false;

  if (layer == 0) {
    // ---------------- layer 0 ----------------
    const uint* hsrc_base = xpk0 + (u64)srow * TT * HC2 + scol;
#pragma unroll 1
    for (int t = 0; t < TT; ++t) {
      // prefetch wxb[t] (independent of h) so its latency hides under the wait
      float wpre[4] = {0.f, 0.f, 0.f, 0.f};
      if (q < 2) {
#pragma unroll
        for (int r = 0; r < 4; ++r)
          wpre[r] = wxb[((u64)(q * 4 + r) * TT + t) * HC2 + j];
      }

      f32x4 acc0 = {0.f, 0.f, 0.f, 0.f}, acc1 = acc0, acc2 = acc0;
      if (t > 0) {
        const uint* src = hsrc_base + (u64)(t - 1) * HC2;
        uint4 p0, p1, p2, p3;
        int spin = 0;
        // flag spin: one hot line, all lanes same word
        const uint* fp = flag0 + (t - 1);
        for (;;) {
          uint fv = ld1_sys(fp);
          if (__ballot(timeout || fv >= WAVES_PER_LAYER) == ~0ull) break;
          if (++spin > (1 << 20)) { timeout = true; break; }
          __builtin_amdgcn_s_sleep(1);
        }
        // data load (ready) + sentinel backstop verify
        spin = 0;
        for (;;) {
          ld16_sys(src, p0, p1, p2, p3);
          bool ok = timeout ||
                    (p0.x != SENT && p0.y != SENT && p0.z != SENT && p0.w != SENT &&
                     p1.x != SENT && p1.y != SENT && p1.z != SENT && p1.w != SENT &&
                     p2.x != SENT && p2.y != SENT && p2.z != SENT && p2.w != SENT &&
                     p3.x != SENT && p3.y != SENT && p3.z != SENT && p3.w != SENT);
          if (__ballot(ok) == ~0ull) break;
          if (++spin > (1 << 20)) { timeout = true; break; }
        }
        { // stage into LDS hi/lo planes
          uint pcs[16] = {p0.x, p0.y, p0.z, p0.w, p1.x, p1.y, p1.z, p1.w,
                          p2.x, p2.y, p2.z, p2.w, p3.x, p3.y, p3.z, p3.w};
          U4 h0, h1, l0, l1;
#pragma unroll
          for (int e = 0; e < 4; ++e) {
            h0.u[e] = (pcs[2 * e] & 0xffffu) | (pcs[2 * e + 1] << 16);
            l0.u[e] = (pcs[2 * e] >> 16) | (pcs[2 * e + 1] & 0xffff0000u);
            h1.u[e] = (pcs[8 + 2 * e] & 0xffffu) | (pcs[8 + 2 * e + 1] << 16);
            l1.u[e] = (pcs[8 + 2 * e] >> 16) | (pcs[8 + 2 * e + 1] & 0xffff0000u);
          }
          *(uint4*)&xah[srow][scol] = h0.q;  *(uint4*)&xah[srow][scol + 8] = h1.q;
          *(uint4*)&xal[srow][scol] = l0.q;  *(uint4*)&xal[srow][scol + 8] = l1.q;
        }
        __syncthreads();                  // the single per-step barrier
#pragma unroll
        for (int ks = 0; ks < 16; ++ks) {
          const int k0 = ks * 32 + q * 8;
          s16x8 ah = *(const s16x8*)&xah[cl][k0];
          s16x8 al = *(const s16x8*)&xal[cl][k0];
          U4 tb, tc;
          tb.q = bh4[ks];
          tc.q = bl4[ks];
          acc0 = __builtin_amdgcn_mfma_f32_16x16x32_bf16(ah, tb.v, acc0, 0, 0, 0);
          acc1 = __builtin_amdgcn_mfma_f32_16x16x32_bf16(al, tb.v, acc1, 0, 0, 0);
          acc2 = __builtin_amdgcn_mfma_f32_16x16x32_bf16(ah, tc.v, acc2, 0, 0, 0);
        }
      }
      if (q < 2) {
#pragma unroll
        for (int r = 0; r < 4; ++r) {
          const int b = q * 4 + r;
          const u64 off = ((u64)b * TT + t) * HC2 + j;
          float y = acc0[r] + acc1[r] + acc2[r] + wpre[r];
          float h = fast_tanh(y);
          st_sys(xpk0 + off, pack_split(h));
        }
      }
      // release: stores ACKed at coherent point, then signal readiness
      release_fence();
      if (lane == 0) atomicAdd(flag0 + t, 1u);
    }
  } else {
    // ---------------- layer 1: y = W1*h0(t) + U1*h1(t-1) + bias1 ----------------
    const uint* h0src_base = xpk0 + (u64)srow * TT * HC2 + scol;
    const uint* h1src_base = h1x + (u64)srow * TT * HC2 + scol;
    const float bv = bias1[j];
#pragma unroll 1
    for (int t = 0; t < TT; ++t) {
      const uint* s0p = h0src_base + (u64)t * HC2;
      uint4 q0, q1, q2, q3, p0, p1, p2, p3;
      int spin = 0;
      if (t == 0) {
        // h1(-1) = 0 (h_init): stage zero planes, wait only on h0(0).
        p0 = make_uint4(0u, 0u, 0u, 0u); p1 = p0; p2 = p0; p3 = p0;
        const uint* fp = flag0 + t;
        for (;;) {
          uint fv = ld1_sys(fp);
          if (__ballot(timeout || fv >= WAVES_PER_LAYER) == ~0ull) break;
          if (++spin > (1 << 20)) { timeout = true; break; }
          __builtin_amdgcn_s_sleep(1);
        }
        spin = 0;
        for (;;) {
          ld16_sys(s0p, q0, q1, q2, q3);
          bool ok = timeout ||
                    (q0.x != SENT && q0.y != SENT && q0.z != SENT && q0.w != SENT &&
                     q1.x != SENT && q1.y != SENT && q1.z != SENT && q1.w != SENT &&
                     q2.x != SENT && q2.y != SENT && q2.z != SENT && q2.w != SENT &&
                     q3.x != SENT && q3.y != SENT && q3.z != SENT && q3.w != SENT);
          if (__ballot(ok) == ~0ull) break;
          if (++spin > (1 << 20)) { timeout = true; break; }
        }
      } else {
        const uint* s1p = h1src_base + (u64)(t - 1) * HC2;
        // flag spin on BOTH counters (two hot lines)
        const uint* fp0 = flag0 + t;
        const uint* fp1 = flag1 + (t - 1);
        for (;;) {
          uint f0v = ld1_sys(fp0);
          uint f1v = ld1_sys(fp1);
          if (__ballot(timeout || (f0v >= WAVES_PER_LAYER && f1v >= WAVES_PER_LAYER)) == ~0ull) break;
          if (++spin > (1 << 20)) { timeout = true; break; }
          __builtin_amdgcn_s_sleep(1);
        }
        // data load + backstop verify of both streams
        spin = 0;
        for (;;) {
          ld32_sys(s0p, s1p, q0, q1, q2, q3, p0, p1, p2, p3);
          bool ok = timeout ||
                    (q0.x != SENT && q0.y != SENT && q0.z != SENT && q0.w != SENT &&
                     q1.x != SENT && q1.y != SENT && q1.z != SENT && q1.w != SENT &&
                     q2.x != SENT && q2.y != SENT && q2.z != SENT && q2.w != SENT &&
                     q3.x != SENT && q3.y != SENT && q3.z != SENT && q3.w != SENT &&
                     p0.x != SENT && p0.y != SENT && p0.z != SENT && p0.w != SENT &&
                     p1.x != SENT && p1.y != SENT && p1.z != SENT && p1.w != SENT &&
                     p2.x != SENT && p2.y != SENT && p2.z != SENT && p2.w != SENT &&
                     p3.x != SENT && p3.y != SENT && p3.z != SENT && p3.w != SENT);
          if (__ballot(ok) == ~0ull) break;
          if (++spin > (1 << 20)) { timeout = true; break; }
        }
      }
      { // stage h0(t) (packed-split words) into yah/yal
        uint pcs[16] = {q0.x, q0.y, q0.z, q0.w, q1.x, q1.y, q1.z, q1.w,
                        q2.x, q2.y, q2.z, q2.w, q3.x, q3.y, q3.z, q3.w};
        U4 h0, h1, l0, l1;
#pragma unroll
        for (int e = 0; e < 4; ++e) {
          h0.u[e] = (pcs[2 * e] & 0xffffu) | (pcs[2 * e + 1] << 16);
          l0.u[e] = (pcs[2 * e] >> 16) | (pcs[2 * e + 1] & 0xffff0000u);
          h1.u[e] = (pcs[8 + 2 * e] & 0xffffu) | (pcs[8 + 2 * e + 1] << 16);
          l1.u[e] = (pcs[8 + 2 * e] >> 16) | (pcs[8 + 2 * e + 1] & 0xffff0000u);
        }
        *(uint4*)&yah[srow][scol] = h0.q;  *(uint4*)&yah[srow][scol + 8] = h1.q;
        *(uint4*)&yal[srow][scol] = l0.q;  *(uint4*)&yal[srow][scol + 8] = l1.q;
      }
      { // stage h1(t-1) (floats) into xah/xal, re-deriving hi/lo split
        // (bit-identical to what the producer would have packed)
        uint pf[16] = {p0.x, p0.y, p0.z, p0.w, p1.x, p1.y, p1.z, p1.w,
                       p2.x, p2.y, p2.z, p2.w, p3.x, p3.y, p3.z, p3.w};
        U4 H0, H1, L0, L1;
#pragma unroll
        for (int e = 0; e < 4; ++e) {
          float fa = __uint_as_float(pf[2 * e]);
          float fb = __uint_as_float(pf[2 * e + 1]);
          uint ha = bf16_rne(fa), hb = bf16_rne(fb);
          uint la = bf16_rne(fa - __uint_as_float(ha << 16));
          uint lb = bf16_rne(fb - __uint_as_float(hb << 16));
          H0.u[e] = ha | (hb << 16);
          L0.u[e] = la | (lb << 16);
          float fc = __uint_as_float(pf[8 + 2 * e]);
          float fd = __uint_as_float(pf[8 + 2 * e + 1]);
          uint hc = bf16_rne(fc), hd = bf16_rne(fd);
          uint lc = bf16_rne(fc - __uint_as_float(hc << 16));
          uint ld = bf16_rne(fd - __uint_as_float(hd << 16));
          H1.u[e] = hc | (hd << 16);
          L1.u[e] = lc | (ld << 16);
        }
        *(uint4*)&xah[srow][scol] = H0.q;  *(uint4*)&xah[srow][scol + 8] = H1.q;
        *(uint4*)&xal[srow][scol] = L0.q;  *(uint4*)&xal[srow][scol + 8] = L1.q;
      }
      __syncthreads();                    // the single per-step barrier

      f32x4 aU0 = {0.f, 0.f, 0.f, 0.f}, aU1 = aU0, aU2 = aU0;
      f32x4 aW0 = aU0, aW1 = aU0, aW2 = aU0;
#pragma unroll
      for (int ks = 0; ks < 16; ++ks) {
        const int k0 = ks * 32 + q * 8;
        s16x8 ah = *(const s16x8*)&xah[cl][k0];
        s16x8 al = *(const s16x8*)&xal[cl][k0];
        s16x8 yh = *(const s16x8*)&yah[cl][k0];
        s16x8 yl = *(const s16x8*)&yal[cl][k0];
        U4 tb, tc, td, te;
        tb.q = bh4[ks]; tc.q = bl4[ks];
        td.q = ch4[ks]; te.q = cl4[ks];
        aU0 = __builtin_amdgcn_mfma_f32_16x16x32_bf16(ah, tb.v, aU0, 0, 0, 0);
        aW0 = __builtin_amdgcn_mfma_f32_16x16x32_bf16(yh, td.v, aW0, 0, 0, 0);
        aU1 = __builtin_amdgcn_mfma_f32_16x16x32_bf16(al, tb.v, aU1, 0, 0, 0);
        aW1 = __builtin_amdgcn_mfma_f32_16x16x32_bf16(yl, td.v, aW1, 0, 0, 0);
        aU2 = __builtin_amdgcn_mfma_f32_16x16x32_bf16(ah, tc.v, aU2, 0, 0, 0);
        aW2 = __builtin_amdgcn_mfma_f32_16x16x32_bf16(yh, te.v, aW2, 0, 0, 0);
      }
      if (q < 2) {
#pragma unroll
        for (int r = 0; r < 4; ++r) {
          const int b = q * 4 + r;
          const u64 off = ((u64)b * TT + t) * HC2 + j;
          float y = aU0[r] + aU1[r] + aU2[r] + aW0[r] + aW1[r] + aW2[r] + bv;
          float h = fast_tanh(y);
          st_sys(h1x + off, __float_as_uint(h));   // float h1: exchange AND final output
        }
      }
      // release + signal
      release_fence();
      if (lane == 0) atomicAdd(flag1 + t, 1u);
    }
  }
}

// ---------- host ----------
extern "C" void kernel_launch(void* const* d_in, const int* in_sizes, int n_in,
                              void* d_out, int out_size, void* d_ws, size_t ws_size,
                              hipStream_t stream) {
  const float* x = (const float*)d_in[0];
  const float* L0[8]; const float* L1[8];
  for (int i = 0; i < 8; ++i) { L0[i] = (const float*)d_in[1 + i]; L1[i] = (const float*)d_in[9 + i]; }

  char* ws = (char*)d_ws;
  const size_t MB = 1024 * 1024;
  uint* MwT0 = (uint*)(ws + 0 * MB);
  uint* MuT0 = (uint*)(ws + 1 * MB);
  uint* MwT1 = (uint*)(ws + 2 * MB);
  uint* MuT1 = (uint*)(ws + 3 * MB);
  float* bias0 = (float*)(ws + 4 * MB);
  float* bias1 = (float*)(ws + 4 * MB + 8192);
  uint* flag0 = (uint*)(ws + 5 * MB);            // [TT] ready counters, layer 0
  uint* flag1 = (uint*)(ws + 5 * MB + TT * 4);   // [TT] ready counters, layer 1
  uint* Apk = (uint*)(ws + 8 * MB);      // 64 MB: packed x -> packed h0 (exchange)
  float* wx = (float*)(ws + 72 * MB);    // 64 MB: layer-0 projection output

  pack_weights_kernel<<<1024, 256, 0, stream>>>(L0[0], L0[1], L0[2], L0[3], L0[4], L0[5], L0[6], L0[7],
                                                MwT0, MuT0, bias0);
  pack_weights_kernel<<<1024, 256, 0, stream>>>(L1[0], L1[1], L1[2], L1[3], L1[4], L1[5], L1[6], L1[7],
                                                MwT1, MuT1, bias1);
  pack_x_kernel<<<16384, 256, 0, stream>>>(x, Apk);
  // layer-0 input projection (big parallel GEMM)
  gemm_split_kernel<<<dim3(256, 4), 256, 0, stream>>>(Apk, MwT0, bias0, wx);
  // poison exchanges (sentinel backstop), zero flags, run the fused scan
  hipMemsetAsync(Apk, 0xFF, 64 * MB, stream);            // h0 packed exchange
  hipMemsetAsync(d_out, 0xFF, 64 * MB, stream);          // h1 float exchange == output
  hipMemsetAsync(flag0, 0, 2 * TT * 4, stream);          // step-ready counters
  fused_scan_kernel<<<16, 256, 0, stream>>>(MuT0, wx, MwT1, MuT1, bias1, Apk, (uint*)d_out,
                                            flag0, flag1);
}

// Round 6
// 12202.110 us; speedup vs baseline: 1.5538x; 1.5538x over previous
//
#include <hip/hip_runtime.h>

typedef unsigned int uint;
typedef unsigned long long u64;
typedef __attribute__((ext_vector_type(4))) float f32x4;
typedef __attribute__((ext_vector_type(8))) short s16x8;   // 8 bf16 in 4 VGPRs

union U4 { uint u[4]; s16x8 v; uint4 q; };

#define TT 4096
#define HC2 512
#define SENT 0xFFFFFFFFu

// ---------- helpers ----------
__device__ __forceinline__ uint bf16_rne(float f) {
  uint x = __float_as_uint(f);
  x += 0x7fffu + ((x >> 16) & 1u);
  return x >> 16;
}
// split f into hi(bf16, low 16 bits) + lo(bf16 of remainder, high 16 bits)
// hi is bf16 of a finite value -> never 0xFFFF (NaN pattern), so a packed
// word can never equal SENT. Float tanh output can likewise never be
// 0xFFFFFFFF (that is a NaN). This is the sentinel protocol's safety.
__device__ __forceinline__ uint pack_split(float f) {
  uint hi = bf16_rne(f);
  float fh = __uint_as_float(hi << 16);
  uint lo = bf16_rne(f - fh);
  return hi | (lo << 16);
}
// inverse of pack_split (exact to the split's precision)
__device__ __forceinline__ float unpack_split(uint w) {
  return __uint_as_float(w << 16) + __uint_as_float(w & 0xffff0000u);
}
__device__ __forceinline__ float fast_tanh(float y) {
  float e = __builtin_amdgcn_exp2f(y * 2.885390081777927f);
  return 1.0f - 2.0f * __builtin_amdgcn_rcpf(e + 1.0f);
}

// system-scope (sc0 sc1): straight to the die-level coherent point. The ONLY
// empirically-validated intra-kernel cross-CU path on this part (R2's
// XCD-pinned sc0/L2 variant regressed 66%; R5's flag protocol added a serial
// RTT and regressed 35% -> both reverted).
__device__ __forceinline__ void st_sys(uint* p, uint v) {
  asm volatile("global_store_dword %0, %1, off sc0 sc1" :: "v"(p), "v"(v) : "memory");
}
__device__ __forceinline__ uint ld1_sys(const uint* p) {
  uint w;
  asm volatile("global_load_dword %0, %1, off sc0 sc1\n\t"
               "s_waitcnt vmcnt(0)" : "=&v"(w) : "v"(p) : "memory");
  return w;
}
__device__ __forceinline__ void ld16_sys(const uint* p, uint4& a, uint4& b, uint4& c, uint4& d) {
  asm volatile("global_load_dwordx4 %0, %4, off sc0 sc1\n\t"
               "global_load_dwordx4 %1, %4, off offset:16 sc0 sc1\n\t"
               "global_load_dwordx4 %2, %4, off offset:32 sc0 sc1\n\t"
               "global_load_dwordx4 %3, %4, off offset:48 sc0 sc1\n\t"
               "s_waitcnt vmcnt(0)"
               : "=&v"(a), "=&v"(b), "=&v"(c), "=&v"(d) : "v"(p) : "memory");
}
// h1 slice (4x dwordx4) + 4 z words (offsets 0/256/512/768 B) in one shot
__device__ __forceinline__ void ld16z_sys(const uint* p, const uint* zp,
                                          uint4& a, uint4& b, uint4& c, uint4& d,
                                          uint& z0, uint& z1, uint& z2, uint& z3) {
  asm volatile("global_load_dwordx4 %0, %8, off sc0 sc1\n\t"
               "global_load_dwordx4 %1, %8, off offset:16 sc0 sc1\n\t"
               "global_load_dwordx4 %2, %8, off offset:32 sc0 sc1\n\t"
               "global_load_dwordx4 %3, %8, off offset:48 sc0 sc1\n\t"
               "global_load_dword %4, %9, off sc0 sc1\n\t"
               "global_load_dword %5, %9, off offset:256 sc0 sc1\n\t"
               "global_load_dword %6, %9, off offset:512 sc0 sc1\n\t"
               "global_load_dword %7, %9, off offset:768 sc0 sc1\n\t"
               "s_waitcnt vmcnt(0)"
               : "=&v"(a), "=&v"(b), "=&v"(c), "=&v"(d),
                 "=&v"(z0), "=&v"(z1), "=&v"(z2), "=&v"(z3)
               : "v"(p), "v"(zp) : "memory");
}
__device__ __forceinline__ void ld2_sys(const uint* pa, const uint* pb, uint& a, uint& b) {
  asm volatile("global_load_dword %0, %2, off sc0 sc1\n\t"
               "global_load_dword %1, %3, off sc0 sc1\n\t"
               "s_waitcnt vmcnt(0)"
               : "=&v"(a), "=&v"(b) : "v"(pa), "v"(pb) : "memory");
}
__device__ __forceinline__ void ld4z_sys(const uint* zp, uint& z0, uint& z1, uint& z2, uint& z3) {
  asm volatile("global_load_dword %0, %4, off sc0 sc1\n\t"
               "global_load_dword %1, %4, off offset:256 sc0 sc1\n\t"
               "global_load_dword %2, %4, off offset:512 sc0 sc1\n\t"
               "global_load_dword %3, %4, off offset:768 sc0 sc1\n\t"
               "s_waitcnt vmcnt(0)"
               : "=&v"(z0), "=&v"(z1), "=&v"(z2), "=&v"(z3) : "v"(zp) : "memory");
}

// ---------- pack weights: M[k][j] stored transposed+split as MT[j][k] (uint32) ----------
__global__ void pack_weights_kernel(const float* __restrict__ wr, const float* __restrict__ wi,
                                    const float* __restrict__ wbr, const float* __restrict__ wbi,
                                    const float* __restrict__ ur, const float* __restrict__ ui,
                                    const float* __restrict__ ubr, const float* __restrict__ ubi,
                                    uint* __restrict__ MwT, uint* __restrict__ MuT,
                                    float* __restrict__ bias) {
  const int id = blockIdx.x * 256 + threadIdx.x;   // 0..262143
  const int j = id >> 9, k = id & 511;
  const int jj = j & 255, kk = k & 255;
  float mw, mu;
  if (k < 256) {
    if (j < 256) { mw =  wr[kk * 256 + jj]; mu =  ur[kk * 256 + jj]; }
    else         { mw =  wi[kk * 256 + jj]; mu =  ui[kk * 256 + jj]; }
  } else {
    if (j < 256) { mw = -wi[kk * 256 + jj]; mu = -ui[kk * 256 + jj]; }
    else         { mw =  wr[kk * 256 + jj]; mu =  ur[kk * 256 + jj]; }
  }
  MwT[id] = pack_split(mw);
  MuT[id] = pack_split(mu);
  if (id < 512)
    bias[id] = (id < 256) ? (wbr[id] + ubr[id]) : (wbi[id - 256] + ubi[id - 256]);
}

// ---------- pack x (fp32 -> split uint32) ----------
__global__ void pack_x_kernel(const float* __restrict__ x, uint* __restrict__ xp) {
  const u64 i = ((u64)blockIdx.x * 256 + threadIdx.x) * 4;
  float4 v = *(const float4*)(x + i);
  uint4 o;
  o.x = pack_split(v.x); o.y = pack_split(v.y);
  o.z = pack_split(v.z); o.w = pack_split(v.w);
  *(uint4*)(xp + i) = o;
}

// ---------- split-bf16 MFMA GEMM:  C[32768][512] = A[32768][512] * B[512][512] + bias ----------
__global__ __launch_bounds__(256, 2)
void gemm_split_kernel(const uint* __restrict__ A, const uint* __restrict__ BT,
                       const float* __restrict__ bias, float* __restrict__ C) {
  __shared__ __align__(16) uint a_s[128][36];
  __shared__ __align__(16) uint b_s[128][36];
  const int tid = threadIdx.x;
  const int wv = tid >> 6, lane = tid & 63;
  const int q = lane >> 4, cl = lane & 15;
  const int row0 = (int)blockIdx.x * 128, col0 = (int)blockIdx.y * 128;
  const int wro = (wv >> 1) * 64, wco = (wv & 1) * 64;
  const int sr = tid >> 1, sc = (tid & 1) * 16;

  f32x4 acc[4][4];
#pragma unroll
  for (int a = 0; a < 4; ++a)
#pragma unroll
    for (int b = 0; b < 4; ++b) acc[a][b] = (f32x4){0.f, 0.f, 0.f, 0.f};

  const uint* ga = A + (u64)(row0 + sr) * 512 + sc;
  const uint* gb = BT + (u64)(col0 + sr) * 512 + sc;

  for (int kb = 0; kb < 16; ++kb) {
    uint4 va0 = *(const uint4*)(ga + 0), va1 = *(const uint4*)(ga + 4);
    uint4 va2 = *(const uint4*)(ga + 8), va3 = *(const uint4*)(ga + 12);
    uint4 vb0 = *(const uint4*)(gb + 0), vb1 = *(const uint4*)(gb + 4);
    uint4 vb2 = *(const uint4*)(gb + 8), vb3 = *(const uint4*)(gb + 12);
    ga += 32; gb += 32;
    __syncthreads();
    *(uint4*)&a_s[sr][sc + 0] = va0;  *(uint4*)&a_s[sr][sc + 4] = va1;
    *(uint4*)&a_s[sr][sc + 8] = va2;  *(uint4*)&a_s[sr][sc + 12] = va3;
    *(uint4*)&b_s[sr][sc + 0] = vb0;  *(uint4*)&b_s[sr][sc + 4] = vb1;
    *(uint4*)&b_s[sr][sc + 8] = vb2;  *(uint4*)&b_s[sr][sc + 12] = vb3;
    __syncthreads();

    s16x8 ah[4], al[4];
#pragma unroll
    for (int rt = 0; rt < 4; ++rt) {
      const uint* p = &a_s[wro + rt * 16 + cl][q * 8];
      uint4 p0 = *(const uint4*)(p), p1 = *(const uint4*)(p + 4);
      U4 th, tl;
      th.u[0] = (p0.x & 0xffffu) | (p0.y << 16);
      th.u[1] = (p0.z & 0xffffu) | (p0.w << 16);
      th.u[2] = (p1.x & 0xffffu) | (p1.y << 16);
      th.u[3] = (p1.z & 0xffffu) | (p1.w << 16);
      tl.u[0] = (p0.x >> 16) | (p0.y & 0xffff0000u);
      tl.u[1] = (p0.z >> 16) | (p0.w & 0xffff0000u);
      tl.u[2] = (p1.x >> 16) | (p1.y & 0xffff0000u);
      tl.u[3] = (p1.z >> 16) | (p1.w & 0xffff0000u);
      ah[rt] = th.v; al[rt] = tl.v;
    }
#pragma unroll
    for (int ct = 0; ct < 4; ++ct) {
      const uint* p = &b_s[wco + ct * 16 + cl][q * 8];
      uint4 p0 = *(const uint4*)(p), p1 = *(const uint4*)(p + 4);
      U4 th, tl;
      th.u[0] = (p0.x & 0xffffu) | (p0.y << 16);
      th.u[1] = (p0.z & 0xffffu) | (p0.w << 16);
      th.u[2] = (p1.x & 0xffffu) | (p1.y << 16);
      th.u[3] = (p1.z & 0xffffu) | (p1.w << 16);
      tl.u[0] = (p0.x >> 16) | (p0.y & 0xffff0000u);
      tl.u[1] = (p0.z >> 16) | (p0.w & 0xffff0000u);
      tl.u[2] = (p1.x >> 16) | (p1.y & 0xffff0000u);
      tl.u[3] = (p1.z >> 16) | (p1.w & 0xffff0000u);
#pragma unroll
      for (int rt = 0; rt < 4; ++rt) {
        acc[rt][ct] = __builtin_amdgcn_mfma_f32_16x16x32_bf16(ah[rt], th.v, acc[rt][ct], 0, 0, 0);
        acc[rt][ct] = __builtin_amdgcn_mfma_f32_16x16x32_bf16(al[rt], th.v, acc[rt][ct], 0, 0, 0);
        acc[rt][ct] = __builtin_amdgcn_mfma_f32_16x16x32_bf16(ah[rt], tl.v, acc[rt][ct], 0, 0, 0);
      }
    }
  }
#pragma unroll
  for (int ct = 0; ct < 4; ++ct) {
    const int col = col0 + wco + ct * 16 + cl;
    const float bv = bias[col];
#pragma unroll
    for (int rt = 0; rt < 4; ++rt) {
      const int rbase = row0 + wro + rt * 16 + q * 4;
#pragma unroll
      for (int r2 = 0; r2 < 4; ++r2)
        C[(u64)(rbase + r2) * 512 + col] = acc[rt][ct][r2] + bv;
    }
  }
}

// ---------- fused 3-stage scan: 24 persistent blocks ----------
// role 0 (blocks 0..7)  : L0 scan (R4 code, proven). h0 -> xpk0 (packed).
// role 1 (blocks 8..15) : W-proj: z(t) = W1*h0(t) + bias1 for own 64 cols.
//                         Feed-forward (no self-recurrence) -> runs at the
//                         h0 stream's pace, always ahead of role 2.
//                         z -> zbuf packed-split (2 KB/block/tick, 1:1 pair).
// role 2 (blocks 16..23): U-scan: h1(t) = tanh(z(t) + U1*h1(t-1)). The
//                         critical loop is now RTT + 48 MFMA (was 96).
//                         h1 -> d_out as float (exchange AND output).
// WAR safety: L0/U gates include their own block's published columns, so a
// wave stages step t only after its own waves' step t-1 LDS reads completed.
// W's gate (h0) is external -> extra barrier after MFMA before next staging.
// All spins bounded + sticky wave-uniform timeout -> no hang possible.
__global__ __launch_bounds__(256, 1)
void fused_scan_kernel(const uint* __restrict__ MuT0, const float* __restrict__ wxb,
                       const uint* __restrict__ MwT1, const uint* __restrict__ MuT1,
                       const float* __restrict__ bias1,
                       uint* __restrict__ xpk0,     // packed h0 exchange (64 MB)
                       uint* __restrict__ h1x,      // d_out as uint: float h1 exchange + output
                       uint* __restrict__ zbuf) {   // packed z exchange (64 MB)
  __shared__ __align__(16) unsigned short xah[16][520];  // hi plane
  __shared__ __align__(16) unsigned short xal[16][520];  // lo plane
  const int tid = threadIdx.x;
  const int wv = tid >> 6, lane = tid & 63;
  const int q = lane >> 4, cl = lane & 15;
  const int role = (int)blockIdx.x >> 3;           // 0=L0, 1=W, 2=U
  const int blk = (int)blockIdx.x & 7;
  const int j = blk * 64 + wv * 16 + cl;           // this lane's output column
  const int jc = wv * 16 + cl;                     // col within block [0,64)

  for (int idx = tid; idx < 16 * 520; idx += 256) {
    ((unsigned short*)xah)[idx] = 0; ((unsigned short*)xal)[idx] = 0;
  }

  // this role's single weight matrix -> registers (B-frags: col=lane&15, k=q*8+e)
  uint4 bh4[16], bl4[16];
  {
    const uint* wsel = (role == 0) ? MuT0 : ((role == 1) ? MwT1 : MuT1);
    const uint* wrow = wsel + (u64)j * 512;
#pragma unroll
    for (int ks = 0; ks < 16; ++ks) {
      const int k0 = ks * 32 + q * 8;
      uint4 p0 = *(const uint4*)(wrow + k0);
      uint4 p1 = *(const uint4*)(wrow + k0 + 4);
      uint4 h, l;
      h.x = (p0.x & 0xffffu) | (p0.y << 16);
      h.y = (p0.z & 0xffffu) | (p0.w << 16);
      h.z = (p1.x & 0xffffu) | (p1.y << 16);
      h.w = (p1.z & 0xffffu) | (p1.w << 16);
      l.x = (p0.x >> 16) | (p0.y & 0xffff0000u);
      l.y = (p0.z >> 16) | (p0.w & 0xffff0000u);
      l.z = (p1.x >> 16) | (p1.y & 0xffff0000u);
      l.w = (p1.z >> 16) | (p1.w & 0xffff0000u);
      bh4[ks] = h; bl4[ks] = l;
    }
  }
  __syncthreads();

  const int srow = tid >> 5;            // staging: 32 threads per batch row
  const int scol = (tid & 31) * 16;
  bool timeout = false;

  if (role == 0) {
    // ================ L0 (R4-proven two-phase poll scan) ================
    const uint* hsrc_base = xpk0 + (u64)srow * TT * HC2 + scol;
#pragma unroll 1
    for (int t = 0; t < TT; ++t) {
      float wpre[4] = {0.f, 0.f, 0.f, 0.f};
      if (q < 2) {
#pragma unroll
        for (int r = 0; r < 4; ++r)
          wpre[r] = wxb[((u64)(q * 4 + r) * TT + t) * HC2 + j];
      }
      f32x4 acc0 = {0.f, 0.f, 0.f, 0.f}, acc1 = acc0, acc2 = acc0;
      if (t > 0) {
        const uint* src = hsrc_base + (u64)(t - 1) * HC2;
        uint4 p0, p1, p2, p3;
        int spin = 0;
        for (;;) {                                   // light spin
          uint w = ld1_sys(src);
          if (__ballot(timeout || w != SENT) == ~0ull) break;
          if (++spin > (1 << 20)) { timeout = true; break; }
          __builtin_amdgcn_s_sleep(1);
        }
        spin = 0;
        for (;;) {                                   // full verify
          ld16_sys(src, p0, p1, p2, p3);
          bool ok = timeout ||
                    (p0.x != SENT && p0.y != SENT && p0.z != SENT && p0.w != SENT &&
                     p1.x != SENT && p1.y != SENT && p1.z != SENT && p1.w != SENT &&
                     p2.x != SENT && p2.y != SENT && p2.z != SENT && p2.w != SENT &&
                     p3.x != SENT && p3.y != SENT && p3.z != SENT && p3.w != SENT);
          if (__ballot(ok) == ~0ull) break;
          if (++spin > (1 << 20)) { timeout = true; break; }
        }
        { // stage packed words into hi/lo planes
          uint pcs[16] = {p0.x, p0.y, p0.z, p0.w, p1.x, p1.y, p1.z, p1.w,
                          p2.x, p2.y, p2.z, p2.w, p3.x, p3.y, p3.z, p3.w};
          U4 h0, h1, l0, l1;
#pragma unroll
          for (int e = 0; e < 4; ++e) {
            h0.u[e] = (pcs[2 * e] & 0xffffu) | (pcs[2 * e + 1] << 16);
            l0.u[e] = (pcs[2 * e] >> 16) | (pcs[2 * e + 1] & 0xffff0000u);
            h1.u[e] = (pcs[8 + 2 * e] & 0xffffu) | (pcs[8 + 2 * e + 1] << 16);
            l1.u[e] = (pcs[8 + 2 * e] >> 16) | (pcs[8 + 2 * e + 1] & 0xffff0000u);
          }
          *(uint4*)&xah[srow][scol] = h0.q;  *(uint4*)&xah[srow][scol + 8] = h1.q;
          *(uint4*)&xal[srow][scol] = l0.q;  *(uint4*)&xal[srow][scol + 8] = l1.q;
        }
        __syncthreads();
#pragma unroll
        for (int ks = 0; ks < 16; ++ks) {
          const int k0 = ks * 32 + q * 8;
          s16x8 ah = *(const s16x8*)&xah[cl][k0];
          s16x8 al = *(const s16x8*)&xal[cl][k0];
          U4 tb, tc; tb.q = bh4[ks]; tc.q = bl4[ks];
          acc0 = __builtin_amdgcn_mfma_f32_16x16x32_bf16(ah, tb.v, acc0, 0, 0, 0);
          acc1 = __builtin_amdgcn_mfma_f32_16x16x32_bf16(al, tb.v, acc1, 0, 0, 0);
          acc2 = __builtin_amdgcn_mfma_f32_16x16x32_bf16(ah, tc.v, acc2, 0, 0, 0);
        }
      }
      if (q < 2) {
#pragma unroll
        for (int r = 0; r < 4; ++r) {
          const int b = q * 4 + r;
          const u64 off = ((u64)b * TT + t) * HC2 + j;
          float y = acc0[r] + acc1[r] + acc2[r] + wpre[r];
          st_sys(xpk0 + off, pack_split(fast_tanh(y)));
        }
      }
    }
  } else if (role == 1) {
    // ================ W-proj: z(t) = W1*h0(t) + bias1 (own 64 cols) ================
    const uint* h0src_base = xpk0 + (u64)srow * TT * HC2 + scol;
    const float bv = bias1[j];
#pragma unroll 1
    for (int t = 0; t < TT; ++t) {
      const uint* src = h0src_base + (u64)t * HC2;
      uint4 p0, p1, p2, p3;
      int spin = 0;
      for (;;) {                                     // light spin
        uint w = ld1_sys(src);
        if (__ballot(timeout || w != SENT) == ~0ull) break;
        if (++spin > (1 << 20)) { timeout = true; break; }
        __builtin_amdgcn_s_sleep(1);
      }
      spin = 0;
      for (;;) {                                     // full verify
        ld16_sys(src, p0, p1, p2, p3);
        bool ok = timeout ||
                  (p0.x != SENT && p0.y != SENT && p0.z != SENT && p0.w != SENT &&
                   p1.x != SENT && p1.y != SENT && p1.z != SENT && p1.w != SENT &&
                   p2.x != SENT && p2.y != SENT && p2.z != SENT && p2.w != SENT &&
                   p3.x != SENT && p3.y != SENT && p3.z != SENT && p3.w != SENT);
        if (__ballot(ok) == ~0ull) break;
        if (++spin > (1 << 20)) { timeout = true; break; }
      }
      { // stage packed words into hi/lo planes
        uint pcs[16] = {p0.x, p0.y, p0.z, p0.w, p1.x, p1.y, p1.z, p1.w,
                        p2.x, p2.y, p2.z, p2.w, p3.x, p3.y, p3.z, p3.w};
        U4 h0, h1, l0, l1;
#pragma unroll
        for (int e = 0; e < 4; ++e) {
          h0.u[e] = (pcs[2 * e] & 0xffffu) | (pcs[2 * e + 1] << 16);
          l0.u[e] = (pcs[2 * e] >> 16) | (pcs[2 * e + 1] & 0xffff0000u);
          h1.u[e] = (pcs[8 + 2 * e] & 0xffffu) | (pcs[8 + 2 * e + 1] << 16);
          l1.u[e] = (pcs[8 + 2 * e] >> 16) | (pcs[8 + 2 * e + 1] & 0xffff0000u);
        }
        *(uint4*)&xah[srow][scol] = h0.q;  *(uint4*)&xah[srow][scol + 8] = h1.q;
        *(uint4*)&xal[srow][scol] = l0.q;  *(uint4*)&xal[srow][scol + 8] = l1.q;
      }
      __syncthreads();                               // barrier 1: staged
      f32x4 a0 = {0.f, 0.f, 0.f, 0.f}, a1 = a0, a2 = a0;
#pragma unroll
      for (int ks = 0; ks < 16; ++ks) {
        const int k0 = ks * 32 + q * 8;
        s16x8 yh = *(const s16x8*)&xah[cl][k0];
        s16x8 yl = *(const s16x8*)&xal[cl][k0];
        U4 tb, tc; tb.q = bh4[ks]; tc.q = bl4[ks];
        a0 = __builtin_amdgcn_mfma_f32_16x16x32_bf16(yh, tb.v, a0, 0, 0, 0);
        a1 = __builtin_amdgcn_mfma_f32_16x16x32_bf16(yl, tb.v, a1, 0, 0, 0);
        a2 = __builtin_amdgcn_mfma_f32_16x16x32_bf16(yh, tc.v, a2, 0, 0, 0);
      }
      if (q < 2) {
        uint* zo = zbuf + (((u64)blk * TT + t) * 8 + q * 4) * 64 + jc;
#pragma unroll
        for (int r = 0; r < 4; ++r) {
          float z = a0[r] + a1[r] + a2[r] + bv;
          st_sys(zo + r * 64, pack_split(z));
        }
      }
      __syncthreads();   // barrier 2: external gate -> protect planes (WAR)
    }
  } else {
    // ================ U-scan: h1(t) = tanh(z(t) + U1*h1(t-1)) ================
    const uint* h1src_base = h1x + (u64)srow * TT * HC2 + scol;
#pragma unroll 1
    for (int t = 0; t < TT; ++t) {
      // per-epilogue-lane z pointer (q<2 lanes; others clamped to a safe addr)
      const uint* zp = zbuf + ((q < 2) ? ((((u64)blk * TT + t) * 8 + q * 4) * 64 + jc) : 0);
      uint zw0, zw1, zw2, zw3;
      int spin = 0;
      if (t == 0) {
        // h1(-1)=0: planes already zeroed; wait only on z(0)
        for (;;) {
          uint z0 = ld1_sys(zp);
          if (__ballot(timeout || q >= 2 || z0 != SENT) == ~0ull) break;
          if (++spin > (1 << 20)) { timeout = true; break; }
          __builtin_amdgcn_s_sleep(1);
        }
        spin = 0;
        for (;;) {
          ld4z_sys(zp, zw0, zw1, zw2, zw3);
          bool ok = timeout || q >= 2 ||
                    (zw0 != SENT && zw1 != SENT && zw2 != SENT && zw3 != SENT);
          if (__ballot(ok) == ~0ull) break;
          if (++spin > (1 << 20)) { timeout = true; break; }
        }
        __syncthreads();
      } else {
        const uint* src = h1src_base + (u64)(t - 1) * HC2;
        uint4 p0, p1, p2, p3;
        for (;;) {                                   // light spin: 1 h1 word + 1 z word
          uint w0, z0;
          ld2_sys(src, zp, w0, z0);
          bool ok = timeout || (w0 != SENT && (q >= 2 || z0 != SENT));
          if (__ballot(ok) == ~0ull) break;
          if (++spin > (1 << 20)) { timeout = true; break; }
          __builtin_amdgcn_s_sleep(1);
        }
        spin = 0;
        for (;;) {                                   // full verify: h1 slice + 4 z words
          ld16z_sys(src, zp, p0, p1, p2, p3, zw0, zw1, zw2, zw3);
          bool ok = timeout ||
                    ((p0.x != SENT && p0.y != SENT && p0.z != SENT && p0.w != SENT &&
                      p1.x != SENT && p1.y != SENT && p1.z != SENT && p1.w != SENT &&
                      p2.x != SENT && p2.y != SENT && p2.z != SENT && p2.w != SENT &&
                      p3.x != SENT && p3.y != SENT && p3.z != SENT && p3.w != SENT) &&
                     (q >= 2 ||
                      (zw0 != SENT && zw1 != SENT && zw2 != SENT && zw3 != SENT)));
          if (__ballot(ok) == ~0ull) break;
          if (++spin > (1 << 20)) { timeout = true; break; }
        }
        { // stage h1(t-1) floats -> hi/lo planes (bit-identical re-split)
          uint pf[16] = {p0.x, p0.y, p0.z, p0.w, p1.x, p1.y, p1.z, p1.w,
                         p2.x, p2.y, p2.z, p2.w, p3.x, p3.y, p3.z, p3.w};
          U4 H0, H1, L0, L1;
#pragma unroll
          for (int e = 0; e < 4; ++e) {
            float fa = __uint_as_float(pf[2 * e]);
            float fb = __uint_as_float(pf[2 * e + 1]);
            uint ha = bf16_rne(fa), hb = bf16_rne(fb);
            uint la = bf16_rne(fa - __uint_as_float(ha << 16));
            uint lb = bf16_rne(fb - __uint_as_float(hb << 16));
            H0.u[e] = ha | (hb << 16);
            L0.u[e] = la | (lb << 16);
            float fc = __uint_as_float(pf[8 + 2 * e]);
            float fd = __uint_as_float(pf[8 + 2 * e + 1]);
            uint hc = bf16_rne(fc), hd = bf16_rne(fd);
            uint lc = bf16_rne(fc - __uint_as_float(hc << 16));
            uint ld = bf16_rne(fd - __uint_as_float(hd << 16));
            H1.u[e] = hc | (hd << 16);
            L1.u[e] = lc | (ld << 16);
          }
          *(uint4*)&xah[srow][scol] = H0.q;  *(uint4*)&xah[srow][scol + 8] = H1.q;
          *(uint4*)&xal[srow][scol] = L0.q;  *(uint4*)&xal[srow][scol + 8] = L1.q;
        }
        __syncthreads();
      }
      f32x4 a0 = {0.f, 0.f, 0.f, 0.f}, a1 = a0, a2 = a0;
      if (t > 0) {
#pragma unroll
        for (int ks = 0; ks < 16; ++ks) {
          const int k0 = ks * 32 + q * 8;
          s16x8 ah = *(const s16x8*)&xah[cl][k0];
          s16x8 al = *(const s16x8*)&xal[cl][k0];
          U4 tb, tc; tb.q = bh4[ks]; tc.q = bl4[ks];
          a0 = __builtin_amdgcn_mfma_f32_16x16x32_bf16(ah, tb.v, a0, 0, 0, 0);
          a1 = __builtin_amdgcn_mfma_f32_16x16x32_bf16(al, tb.v, a1, 0, 0, 0);
          a2 = __builtin_amdgcn_mfma_f32_16x16x32_bf16(ah, tc.v, a2, 0, 0, 0);
        }
      }
      if (q < 2) {
        uint zw[4] = {zw0, zw1, zw2, zw3};
#pragma unroll
        for (int r = 0; r < 4; ++r) {
          const int b = q * 4 + r;
          const u64 off = ((u64)b * TT + t) * HC2 + j;
          float y = a0[r] + a1[r] + a2[r] + unpack_split(zw[r]);
          st_sys(h1x + off, __float_as_uint(fast_tanh(y)));
        }
      }
    }
  }
}

// ---------- host ----------
extern "C" void kernel_launch(void* const* d_in, const int* in_sizes, int n_in,
                              void* d_out, int out_size, void* d_ws, size_t ws_size,
                              hipStream_t stream) {
  const float* x = (const float*)d_in[0];
  const float* L0[8]; const float* L1[8];
  for (int i = 0; i < 8; ++i) { L0[i] = (const float*)d_in[1 + i]; L1[i] = (const float*)d_in[9 + i]; }

  char* ws = (char*)d_ws;
  const size_t MB = 1024 * 1024;
  uint* MwT0 = (uint*)(ws + 0 * MB);
  uint* MuT0 = (uint*)(ws + 1 * MB);
  uint* MwT1 = (uint*)(ws + 2 * MB);
  uint* MuT1 = (uint*)(ws + 3 * MB);
  float* bias0 = (float*)(ws + 4 * MB);
  float* bias1 = (float*)(ws + 4 * MB + 8192);
  uint* Apk = (uint*)(ws + 8 * MB);      // 64 MB: packed x -> packed h0 (exchange)
  float* wx = (float*)(ws + 72 * MB);    // 64 MB: layer-0 projection output
  uint* zbuf = (uint*)(ws + 136 * MB);   // 64 MB: packed z = W1*h0 + b1 (exchange)

  pack_weights_kernel<<<1024, 256, 0, stream>>>(L0[0], L0[1], L0[2], L0[3], L0[4], L0[5], L0[6], L0[7],
                                                MwT0, MuT0, bias0);
  pack_weights_kernel<<<1024, 256, 0, stream>>>(L1[0], L1[1], L1[2], L1[3], L1[4], L1[5], L1[6], L1[7],
                                                MwT1, MuT1, bias1);
  pack_x_kernel<<<16384, 256, 0, stream>>>(x, Apk);
  // layer-0 input projection (big parallel GEMM)
  gemm_split_kernel<<<dim3(256, 4), 256, 0, stream>>>(Apk, MwT0, bias0, wx);
  // poison all three exchange buffers, then run the 3-stage fused scan
  hipMemsetAsync(Apk, 0xFF, 64 * MB, stream);            // h0 packed exchange
  hipMemsetAsync(d_out, 0xFF, 64 * MB, stream);          // h1 float exchange == output
  hipMemsetAsync(zbuf, 0xFF, 64 * MB, stream);           // z packed exchange
  fused_scan_kernel<<<24, 256, 0, stream>>>(MuT0, wx, MwT1, MuT1, bias1, Apk, (uint*)d_out, zbuf);
}

// Round 7
// 12046.896 us; speedup vs baseline: 1.5738x; 1.0129x over previous
//
#include <hip/hip_runtime.h>

typedef unsigned int uint;
typedef unsigned long long u64;
typedef __attribute__((ext_vector_type(4))) float f32x4;
typedef __attribute__((ext_vector_type(8))) short s16x8;   // 8 bf16 in 4 VGPRs

union U4 { uint u[4]; s16x8 v; uint4 q; };

#define TT 4096
#define HC2 512
#define SENT 0xFFFFFFFFu

// ---------- helpers ----------
__device__ __forceinline__ uint bf16_rne(float f) {
  uint x = __float_as_uint(f);
  x += 0x7fffu + ((x >> 16) & 1u);
  return x >> 16;
}
// split f into hi(bf16, low 16 bits) + lo(bf16 of remainder, high 16 bits)
// hi is bf16 of a finite value -> never 0xFFFF (NaN pattern), so a packed
// word can never equal SENT. Float tanh output can likewise never be
// 0xFFFFFFFF (that is a NaN). This is the sentinel protocol's safety.
__device__ __forceinline__ uint pack_split(float f) {
  uint hi = bf16_rne(f);
  float fh = __uint_as_float(hi << 16);
  uint lo = bf16_rne(f - fh);
  return hi | (lo << 16);
}
// inverse of pack_split (exact to the split's precision)
__device__ __forceinline__ float unpack_split(uint w) {
  return __uint_as_float(w << 16) + __uint_as_float(w & 0xffff0000u);
}
__device__ __forceinline__ float fast_tanh(float y) {
  float e = __builtin_amdgcn_exp2f(y * 2.885390081777927f);
  return 1.0f - 2.0f * __builtin_amdgcn_rcpf(e + 1.0f);
}

// system-scope (sc0 sc1): straight to the die-level coherent point. The ONLY
// empirically-validated intra-kernel cross-CU path on this part (R2's
// XCD-pinned sc0/L2 variant regressed 66%; R5's flag protocol added a serial
// RTT and regressed 35% -> both reverted).
__device__ __forceinline__ void st_sys(uint* p, uint v) {
  asm volatile("global_store_dword %0, %1, off sc0 sc1" :: "v"(p), "v"(v) : "memory");
}
__device__ __forceinline__ void ld16_sys(const uint* p, uint4& a, uint4& b, uint4& c, uint4& d) {
  asm volatile("global_load_dwordx4 %0, %4, off sc0 sc1\n\t"
               "global_load_dwordx4 %1, %4, off offset:16 sc0 sc1\n\t"
               "global_load_dwordx4 %2, %4, off offset:32 sc0 sc1\n\t"
               "global_load_dwordx4 %3, %4, off offset:48 sc0 sc1\n\t"
               "s_waitcnt vmcnt(0)"
               : "=&v"(a), "=&v"(b), "=&v"(c), "=&v"(d) : "v"(p) : "memory");
}
// h1 slice (4x dwordx4) + 4 z words (offsets 0/256/512/768 B) in one shot
__device__ __forceinline__ void ld16z_sys(const uint* p, const uint* zp,
                                          uint4& a, uint4& b, uint4& c, uint4& d,
                                          uint& z0, uint& z1, uint& z2, uint& z3) {
  asm volatile("global_load_dwordx4 %0, %8, off sc0 sc1\n\t"
               "global_load_dwordx4 %1, %8, off offset:16 sc0 sc1\n\t"
               "global_load_dwordx4 %2, %8, off offset:32 sc0 sc1\n\t"
               "global_load_dwordx4 %3, %8, off offset:48 sc0 sc1\n\t"
               "global_load_dword %4, %9, off sc0 sc1\n\t"
               "global_load_dword %5, %9, off offset:256 sc0 sc1\n\t"
               "global_load_dword %6, %9, off offset:512 sc0 sc1\n\t"
               "global_load_dword %7, %9, off offset:768 sc0 sc1\n\t"
               "s_waitcnt vmcnt(0)"
               : "=&v"(a), "=&v"(b), "=&v"(c), "=&v"(d),
                 "=&v"(z0), "=&v"(z1), "=&v"(z2), "=&v"(z3)
               : "v"(p), "v"(zp) : "memory");
}
__device__ __forceinline__ void ld4z_sys(const uint* zp, uint& z0, uint& z1, uint& z2, uint& z3) {
  asm volatile("global_load_dword %0, %4, off sc0 sc1\n\t"
               "global_load_dword %1, %4, off offset:256 sc0 sc1\n\t"
               "global_load_dword %2, %4, off offset:512 sc0 sc1\n\t"
               "global_load_dword %3, %4, off offset:768 sc0 sc1\n\t"
               "s_waitcnt vmcnt(0)"
               : "=&v"(z0), "=&v"(z1), "=&v"(z2), "=&v"(z3) : "v"(zp) : "memory");
}

// ---------- pack weights: M[k][j] stored transposed+split as MT[j][k] (uint32) ----------
__global__ void pack_weights_kernel(const float* __restrict__ wr, const float* __restrict__ wi,
                                    const float* __restrict__ wbr, const float* __restrict__ wbi,
                                    const float* __restrict__ ur, const float* __restrict__ ui,
                                    const float* __restrict__ ubr, const float* __restrict__ ubi,
                                    uint* __restrict__ MwT, uint* __restrict__ MuT,
                                    float* __restrict__ bias) {
  const int id = blockIdx.x * 256 + threadIdx.x;   // 0..262143
  const int j = id >> 9, k = id & 511;
  const int jj = j & 255, kk = k & 255;
  float mw, mu;
  if (k < 256) {
    if (j < 256) { mw =  wr[kk * 256 + jj]; mu =  ur[kk * 256 + jj]; }
    else         { mw =  wi[kk * 256 + jj]; mu =  ui[kk * 256 + jj]; }
  } else {
    if (j < 256) { mw = -wi[kk * 256 + jj]; mu = -ui[kk * 256 + jj]; }
    else         { mw =  wr[kk * 256 + jj]; mu =  ur[kk * 256 + jj]; }
  }
  MwT[id] = pack_split(mw);
  MuT[id] = pack_split(mu);
  if (id < 512)
    bias[id] = (id < 256) ? (wbr[id] + ubr[id]) : (wbi[id - 256] + ubi[id - 256]);
}

// ---------- pack x (fp32 -> split uint32) ----------
__global__ void pack_x_kernel(const float* __restrict__ x, uint* __restrict__ xp) {
  const u64 i = ((u64)blockIdx.x * 256 + threadIdx.x) * 4;
  float4 v = *(const float4*)(x + i);
  uint4 o;
  o.x = pack_split(v.x); o.y = pack_split(v.y);
  o.z = pack_split(v.z); o.w = pack_split(v.w);
  *(uint4*)(xp + i) = o;
}

// ---------- split-bf16 MFMA GEMM:  C[32768][512] = A[32768][512] * B[512][512] + bias ----------
__global__ __launch_bounds__(256, 2)
void gemm_split_kernel(const uint* __restrict__ A, const uint* __restrict__ BT,
                       const float* __restrict__ bias, float* __restrict__ C) {
  __shared__ __align__(16) uint a_s[128][36];
  __shared__ __align__(16) uint b_s[128][36];
  const int tid = threadIdx.x;
  const int wv = tid >> 6, lane = tid & 63;
  const int q = lane >> 4, cl = lane & 15;
  const int row0 = (int)blockIdx.x * 128, col0 = (int)blockIdx.y * 128;
  const int wro = (wv >> 1) * 64, wco = (wv & 1) * 64;
  const int sr = tid >> 1, sc = (tid & 1) * 16;

  f32x4 acc[4][4];
#pragma unroll
  for (int a = 0; a < 4; ++a)
#pragma unroll
    for (int b = 0; b < 4; ++b) acc[a][b] = (f32x4){0.f, 0.f, 0.f, 0.f};

  const uint* ga = A + (u64)(row0 + sr) * 512 + sc;
  const uint* gb = BT + (u64)(col0 + sr) * 512 + sc;

  for (int kb = 0; kb < 16; ++kb) {
    uint4 va0 = *(const uint4*)(ga + 0), va1 = *(const uint4*)(ga + 4);
    uint4 va2 = *(const uint4*)(ga + 8), va3 = *(const uint4*)(ga + 12);
    uint4 vb0 = *(const uint4*)(gb + 0), vb1 = *(const uint4*)(gb + 4);
    uint4 vb2 = *(const uint4*)(gb + 8), vb3 = *(const uint4*)(gb + 12);
    ga += 32; gb += 32;
    __syncthreads();
    *(uint4*)&a_s[sr][sc + 0] = va0;  *(uint4*)&a_s[sr][sc + 4] = va1;
    *(uint4*)&a_s[sr][sc + 8] = va2;  *(uint4*)&a_s[sr][sc + 12] = va3;
    *(uint4*)&b_s[sr][sc + 0] = vb0;  *(uint4*)&b_s[sr][sc + 4] = vb1;
    *(uint4*)&b_s[sr][sc + 8] = vb2;  *(uint4*)&b_s[sr][sc + 12] = vb3;
    __syncthreads();

    s16x8 ah[4], al[4];
#pragma unroll
    for (int rt = 0; rt < 4; ++rt) {
      const uint* p = &a_s[wro + rt * 16 + cl][q * 8];
      uint4 p0 = *(const uint4*)(p), p1 = *(const uint4*)(p + 4);
      U4 th, tl;
      th.u[0] = (p0.x & 0xffffu) | (p0.y << 16);
      th.u[1] = (p0.z & 0xffffu) | (p0.w << 16);
      th.u[2] = (p1.x & 0xffffu) | (p1.y << 16);
      th.u[3] = (p1.z & 0xffffu) | (p1.w << 16);
      tl.u[0] = (p0.x >> 16) | (p0.y & 0xffff0000u);
      tl.u[1] = (p0.z >> 16) | (p0.w & 0xffff0000u);
      tl.u[2] = (p1.x >> 16) | (p1.y & 0xffff0000u);
      tl.u[3] = (p1.z >> 16) | (p1.w & 0xffff0000u);
      ah[rt] = th.v; al[rt] = tl.v;
    }
#pragma unroll
    for (int ct = 0; ct < 4; ++ct) {
      const uint* p = &b_s[wco + ct * 16 + cl][q * 8];
      uint4 p0 = *(const uint4*)(p), p1 = *(const uint4*)(p + 4);
      U4 th, tl;
      th.u[0] = (p0.x & 0xffffu) | (p0.y << 16);
      th.u[1] = (p0.z & 0xffffu) | (p0.w << 16);
      th.u[2] = (p1.x & 0xffffu) | (p1.y << 16);
      th.u[3] = (p1.z & 0xffffu) | (p1.w << 16);
      tl.u[0] = (p0.x >> 16) | (p0.y & 0xffff0000u);
      tl.u[1] = (p0.z >> 16) | (p0.w & 0xffff0000u);
      tl.u[2] = (p1.x >> 16) | (p1.y & 0xffff0000u);
      tl.u[3] = (p1.z >> 16) | (p1.w & 0xffff0000u);
#pragma unroll
      for (int rt = 0; rt < 4; ++rt) {
        acc[rt][ct] = __builtin_amdgcn_mfma_f32_16x16x32_bf16(ah[rt], th.v, acc[rt][ct], 0, 0, 0);
        acc[rt][ct] = __builtin_amdgcn_mfma_f32_16x16x32_bf16(al[rt], th.v, acc[rt][ct], 0, 0, 0);
        acc[rt][ct] = __builtin_amdgcn_mfma_f32_16x16x32_bf16(ah[rt], tl.v, acc[rt][ct], 0, 0, 0);
      }
    }
  }
#pragma unroll
  for (int ct = 0; ct < 4; ++ct) {
    const int col = col0 + wco + ct * 16 + cl;
    const float bv = bias[col];
#pragma unroll
    for (int rt = 0; rt < 4; ++rt) {
      const int rbase = row0 + wro + rt * 16 + q * 4;
#pragma unroll
      for (int r2 = 0; r2 < 4; ++r2)
        C[(u64)(rbase + r2) * 512 + col] = acc[rt][ct][r2] + bv;
    }
  }
}

// ---------- fused 3-stage scan: 24 persistent blocks ----------
// role 0 (blocks 0..7)  : L0 scan. h0 -> xpk0 (packed).
// role 1 (blocks 8..15) : W-proj: z(t) = W1*h0(t) + bias1 (64 cols each).
// role 2 (blocks 16..23): U-scan: h1(t) = tanh(z(t) + U1*h1(t-1)) -> d_out.
// R7: MERGED full-width poll. The R6 two-phase poll (light spin -> serial
// full load) appended one L3 RTT after discovery. Since the light word sits
// in the same 64B line the full load reads, polling at full width has the
// SAME per-iteration line footprint — and the winning iteration already has
// the data in registers. s_sleep backoff retained (R4's proven win). The
// verify condition is unchanged (every word non-sentinel).
// All spins bounded + sticky wave-uniform timeout -> no hang possible.
__global__ __launch_bounds__(256, 1)
void fused_scan_kernel(const uint* __restrict__ MuT0, const float* __restrict__ wxb,
                       const uint* __restrict__ MwT1, const uint* __restrict__ MuT1,
                       const float* __restrict__ bias1,
                       uint* __restrict__ xpk0,     // packed h0 exchange (64 MB)
                       uint* __restrict__ h1x,      // d_out as uint: float h1 exchange + output
                       uint* __restrict__ zbuf) {   // packed z exchange (64 MB)
  __shared__ __align__(16) unsigned short xah[16][520];  // hi plane
  __shared__ __align__(16) unsigned short xal[16][520];  // lo plane
  const int tid = threadIdx.x;
  const int wv = tid >> 6, lane = tid & 63;
  const int q = lane >> 4, cl = lane & 15;
  const int role = (int)blockIdx.x >> 3;           // 0=L0, 1=W, 2=U
  const int blk = (int)blockIdx.x & 7;
  const int j = blk * 64 + wv * 16 + cl;           // this lane's output column
  const int jc = wv * 16 + cl;                     // col within block [0,64)

  for (int idx = tid; idx < 16 * 520; idx += 256) {
    ((unsigned short*)xah)[idx] = 0; ((unsigned short*)xal)[idx] = 0;
  }

  // this role's single weight matrix -> registers (B-frags: col=lane&15, k=q*8+e)
  uint4 bh4[16], bl4[16];
  {
    const uint* wsel = (role == 0) ? MuT0 : ((role == 1) ? MwT1 : MuT1);
    const uint* wrow = wsel + (u64)j * 512;
#pragma unroll
    for (int ks = 0; ks < 16; ++ks) {
      const int k0 = ks * 32 + q * 8;
      uint4 p0 = *(const uint4*)(wrow + k0);
      uint4 p1 = *(const uint4*)(wrow + k0 + 4);
      uint4 h, l;
      h.x = (p0.x & 0xffffu) | (p0.y << 16);
      h.y = (p0.z & 0xffffu) | (p0.w << 16);
      h.z = (p1.x & 0xffffu) | (p1.y << 16);
      h.w = (p1.z & 0xffffu) | (p1.w << 16);
      l.x = (p0.x >> 16) | (p0.y & 0xffff0000u);
      l.y = (p0.z >> 16) | (p0.w & 0xffff0000u);
      l.z = (p1.x >> 16) | (p1.y & 0xffff0000u);
      l.w = (p1.z >> 16) | (p1.w & 0xffff0000u);
      bh4[ks] = h; bl4[ks] = l;
    }
  }
  __syncthreads();

  const int srow = tid >> 5;            // staging: 32 threads per batch row
  const int scol = (tid & 31) * 16;
  bool timeout = false;

  if (role == 0) {
    // ================ L0 scan ================
    const uint* hsrc_base = xpk0 + (u64)srow * TT * HC2 + scol;
#pragma unroll 1
    for (int t = 0; t < TT; ++t) {
      float wpre[4] = {0.f, 0.f, 0.f, 0.f};
      if (q < 2) {
#pragma unroll
        for (int r = 0; r < 4; ++r)
          wpre[r] = wxb[((u64)(q * 4 + r) * TT + t) * HC2 + j];
      }
      f32x4 acc0 = {0.f, 0.f, 0.f, 0.f}, acc1 = acc0, acc2 = acc0;
      if (t > 0) {
        const uint* src = hsrc_base + (u64)(t - 1) * HC2;
        uint4 p0, p1, p2, p3;
        int spin = 0;
        for (;;) {                       // merged full-width poll + backoff
          ld16_sys(src, p0, p1, p2, p3);
          bool ok = timeout ||
                    (p0.x != SENT && p0.y != SENT && p0.z != SENT && p0.w != SENT &&
                     p1.x != SENT && p1.y != SENT && p1.z != SENT && p1.w != SENT &&
                     p2.x != SENT && p2.y != SENT && p2.z != SENT && p2.w != SENT &&
                     p3.x != SENT && p3.y != SENT && p3.z != SENT && p3.w != SENT);
          if (__ballot(ok) == ~0ull) break;
          if (++spin > (1 << 20)) { timeout = true; break; }
          __builtin_amdgcn_s_sleep(1);
        }
        { // stage packed words into hi/lo planes
          uint pcs[16] = {p0.x, p0.y, p0.z, p0.w, p1.x, p1.y, p1.z, p1.w,
                          p2.x, p2.y, p2.z, p2.w, p3.x, p3.y, p3.z, p3.w};
          U4 h0, h1, l0, l1;
#pragma unroll
          for (int e = 0; e < 4; ++e) {
            h0.u[e] = (pcs[2 * e] & 0xffffu) | (pcs[2 * e + 1] << 16);
            l0.u[e] = (pcs[2 * e] >> 16) | (pcs[2 * e + 1] & 0xffff0000u);
            h1.u[e] = (pcs[8 + 2 * e] & 0xffffu) | (pcs[8 + 2 * e + 1] << 16);
            l1.u[e] = (pcs[8 + 2 * e] >> 16) | (pcs[8 + 2 * e + 1] & 0xffff0000u);
          }
          *(uint4*)&xah[srow][scol] = h0.q;  *(uint4*)&xah[srow][scol + 8] = h1.q;
          *(uint4*)&xal[srow][scol] = l0.q;  *(uint4*)&xal[srow][scol + 8] = l1.q;
        }
        __syncthreads();
#pragma unroll
        for (int ks = 0; ks < 16; ++ks) {
          const int k0 = ks * 32 + q * 8;
          s16x8 ah = *(const s16x8*)&xah[cl][k0];
          s16x8 al = *(const s16x8*)&xal[cl][k0];
          U4 tb, tc; tb.q = bh4[ks]; tc.q = bl4[ks];
          acc0 = __builtin_amdgcn_mfma_f32_16x16x32_bf16(ah, tb.v, acc0, 0, 0, 0);
          acc1 = __builtin_amdgcn_mfma_f32_16x16x32_bf16(al, tb.v, acc1, 0, 0, 0);
          acc2 = __builtin_amdgcn_mfma_f32_16x16x32_bf16(ah, tc.v, acc2, 0, 0, 0);
        }
      }
      if (q < 2) {
#pragma unroll
        for (int r = 0; r < 4; ++r) {
          const int b = q * 4 + r;
          const u64 off = ((u64)b * TT + t) * HC2 + j;
          float y = acc0[r] + acc1[r] + acc2[r] + wpre[r];
          st_sys(xpk0 + off, pack_split(fast_tanh(y)));
        }
      }
    }
  } else if (role == 1) {
    // ================ W-proj: z(t) = W1*h0(t) + bias1 (own 64 cols) ================
    const uint* h0src_base = xpk0 + (u64)srow * TT * HC2 + scol;
    const float bv = bias1[j];
#pragma unroll 1
    for (int t = 0; t < TT; ++t) {
      const uint* src = h0src_base + (u64)t * HC2;
      uint4 p0, p1, p2, p3;
      int spin = 0;
      for (;;) {                         // merged full-width poll + backoff
        ld16_sys(src, p0, p1, p2, p3);
        bool ok = timeout ||
                  (p0.x != SENT && p0.y != SENT && p0.z != SENT && p0.w != SENT &&
                   p1.x != SENT && p1.y != SENT && p1.z != SENT && p1.w != SENT &&
                   p2.x != SENT && p2.y != SENT && p2.z != SENT && p2.w != SENT &&
                   p3.x != SENT && p3.y != SENT && p3.z != SENT && p3.w != SENT);
        if (__ballot(ok) == ~0ull) break;
        if (++spin > (1 << 20)) { timeout = true; break; }
        __builtin_amdgcn_s_sleep(1);
      }
      { // stage packed words into hi/lo planes
        uint pcs[16] = {p0.x, p0.y, p0.z, p0.w, p1.x, p1.y, p1.z, p1.w,
                        p2.x, p2.y, p2.z, p2.w, p3.x, p3.y, p3.z, p3.w};
        U4 h0, h1, l0, l1;
#pragma unroll
        for (int e = 0; e < 4; ++e) {
          h0.u[e] = (pcs[2 * e] & 0xffffu) | (pcs[2 * e + 1] << 16);
          l0.u[e] = (pcs[2 * e] >> 16) | (pcs[2 * e + 1] & 0xffff0000u);
          h1.u[e] = (pcs[8 + 2 * e] & 0xffffu) | (pcs[8 + 2 * e + 1] << 16);
          l1.u[e] = (pcs[8 + 2 * e] >> 16) | (pcs[8 + 2 * e + 1] & 0xffff0000u);
        }
        *(uint4*)&xah[srow][scol] = h0.q;  *(uint4*)&xah[srow][scol + 8] = h1.q;
        *(uint4*)&xal[srow][scol] = l0.q;  *(uint4*)&xal[srow][scol + 8] = l1.q;
      }
      __syncthreads();                               // barrier 1: staged
      f32x4 a0 = {0.f, 0.f, 0.f, 0.f}, a1 = a0, a2 = a0;
#pragma unroll
      for (int ks = 0; ks < 16; ++ks) {
        const int k0 = ks * 32 + q * 8;
        s16x8 yh = *(const s16x8*)&xah[cl][k0];
        s16x8 yl = *(const s16x8*)&xal[cl][k0];
        U4 tb, tc; tb.q = bh4[ks]; tc.q = bl4[ks];
        a0 = __builtin_amdgcn_mfma_f32_16x16x32_bf16(yh, tb.v, a0, 0, 0, 0);
        a1 = __builtin_amdgcn_mfma_f32_16x16x32_bf16(yl, tb.v, a1, 0, 0, 0);
        a2 = __builtin_amdgcn_mfma_f32_16x16x32_bf16(yh, tc.v, a2, 0, 0, 0);
      }
      if (q < 2) {
        uint* zo = zbuf + (((u64)blk * TT + t) * 8 + q * 4) * 64 + jc;
#pragma unroll
        for (int r = 0; r < 4; ++r) {
          float z = a0[r] + a1[r] + a2[r] + bv;
          st_sys(zo + r * 64, pack_split(z));
        }
      }
      __syncthreads();   // barrier 2: external gate -> protect planes (WAR)
    }
  } else {
    // ================ U-scan: h1(t) = tanh(z(t) + U1*h1(t-1)) ================
    const uint* h1src_base = h1x + (u64)srow * TT * HC2 + scol;
#pragma unroll 1
    for (int t = 0; t < TT; ++t) {
      // per-epilogue-lane z pointer (q<2 lanes; others clamped to a safe addr)
      const uint* zp = zbuf + ((q < 2) ? ((((u64)blk * TT + t) * 8 + q * 4) * 64 + jc) : 0);
      uint zw0, zw1, zw2, zw3;
      int spin = 0;
      if (t == 0) {
        // h1(-1)=0: planes already zeroed; wait only on z(0)
        for (;;) {                       // merged poll + backoff
          ld4z_sys(zp, zw0, zw1, zw2, zw3);
          bool ok = timeout || q >= 2 ||
                    (zw0 != SENT && zw1 != SENT && zw2 != SENT && zw3 != SENT);
          if (__ballot(ok) == ~0ull) break;
          if (++spin > (1 << 20)) { timeout = true; break; }
          __builtin_amdgcn_s_sleep(1);
        }
        __syncthreads();
      } else {
        const uint* src = h1src_base + (u64)(t - 1) * HC2;
        uint4 p0, p1, p2, p3;
        for (;;) {                       // merged full-width poll + backoff
          ld16z_sys(src, zp, p0, p1, p2, p3, zw0, zw1, zw2, zw3);
          bool ok = timeout ||
                    ((p0.x != SENT && p0.y != SENT && p0.z != SENT && p0.w != SENT &&
                      p1.x != SENT && p1.y != SENT && p1.z != SENT && p1.w != SENT &&
                      p2.x != SENT && p2.y != SENT && p2.z != SENT && p2.w != SENT &&
                      p3.x != SENT && p3.y != SENT && p3.z != SENT && p3.w != SENT) &&
                     (q >= 2 ||
                      (zw0 != SENT && zw1 != SENT && zw2 != SENT && zw3 != SENT)));
          if (__ballot(ok) == ~0ull) break;
          if (++spin > (1 << 20)) { timeout = true; break; }
          __builtin_amdgcn_s_sleep(1);
        }
        { // stage h1(t-1) floats -> hi/lo planes (bit-identical re-split)
          uint pf[16] = {p0.x, p0.y, p0.z, p0.w, p1.x, p1.y, p1.z, p1.w,
                         p2.x, p2.y, p2.z, p2.w, p3.x, p3.y, p3.z, p3.w};
          U4 H0, H1, L0, L1;
#pragma unroll
          for (int e = 0; e < 4; ++e) {
            float fa = __uint_as_float(pf[2 * e]);
            float fb = __uint_as_float(pf[2 * e + 1]);
            uint ha = bf16_rne(fa), hb = bf16_rne(fb);
            uint la = bf16_rne(fa - __uint_as_float(ha << 16));
            uint lb = bf16_rne(fb - __uint_as_float(hb << 16));
            H0.u[e] = ha | (hb << 16);
            L0.u[e] = la | (lb << 16);
            float fc = __uint_as_float(pf[8 + 2 * e]);
            float fd = __uint_as_float(pf[8 + 2 * e + 1]);
            uint hc = bf16_rne(fc), hd = bf16_rne(fd);
            uint lc = bf16_rne(fc - __uint_as_float(hc << 16));
            uint ld = bf16_rne(fd - __uint_as_float(hd << 16));
            H1.u[e] = hc | (hd << 16);
            L1.u[e] = lc | (ld << 16);
          }
          *(uint4*)&xah[srow][scol] = H0.q;  *(uint4*)&xah[srow][scol + 8] = H1.q;
          *(uint4*)&xal[srow][scol] = L0.q;  *(uint4*)&xal[srow][scol + 8] = L1.q;
        }
        __syncthreads();
      }
      f32x4 a0 = {0.f, 0.f, 0.f, 0.f}, a1 = a0, a2 = a0;
      if (t > 0) {
#pragma unroll
        for (int ks = 0; ks < 16; ++ks) {
          const int k0 = ks * 32 + q * 8;
          s16x8 ah = *(const s16x8*)&xah[cl][k0];
          s16x8 al = *(const s16x8*)&xal[cl][k0];
          U4 tb, tc; tb.q = bh4[ks]; tc.q = bl4[ks];
          a0 = __builtin_amdgcn_mfma_f32_16x16x32_bf16(ah, tb.v, a0, 0, 0, 0);
          a1 = __builtin_amdgcn_mfma_f32_16x16x32_bf16(al, tb.v, a1, 0, 0, 0);
          a2 = __builtin_amdgcn_mfma_f32_16x16x32_bf16(ah, tc.v, a2, 0, 0, 0);
        }
      }
      if (q < 2) {
        uint zw[4] = {zw0, zw1, zw2, zw3};
#pragma unroll
        for (int r = 0; r < 4; ++r) {
          const int b = q * 4 + r;
          const u64 off = ((u64)b * TT + t) * HC2 + j;
          float y = a0[r] + a1[r] + a2[r] + unpack_split(zw[r]);
          st_sys(h1x + off, __float_as_uint(fast_tanh(y)));
        }
      }
    }
  }
}

// ---------- host ----------
extern "C" void kernel_launch(void* const* d_in, const int* in_sizes, int n_in,
                              void* d_out, int out_size, void* d_ws, size_t ws_size,
                              hipStream_t stream) {
  const float* x = (const float*)d_in[0];
  const float* L0[8]; const float* L1[8];
  for (int i = 0; i < 8; ++i) { L0[i] = (const float*)d_in[1 + i]; L1[i] = (const float*)d_in[9 + i]; }

  char* ws = (char*)d_ws;
  const size_t MB = 1024 * 1024;
  uint* MwT0 = (uint*)(ws + 0 * MB);
  uint* MuT0 = (uint*)(ws + 1 * MB);
  uint* MwT1 = (uint*)(ws + 2 * MB);
  uint* MuT1 = (uint*)(ws + 3 * MB);
  float* bias0 = (float*)(ws + 4 * MB);
  float* bias1 = (float*)(ws + 4 * MB + 8192);
  uint* Apk = (uint*)(ws + 8 * MB);      // 64 MB: packed x -> packed h0 (exchange)
  float* wx = (float*)(ws + 72 * MB);    // 64 MB: layer-0 projection output
  uint* zbuf = (uint*)(ws + 136 * MB);   // 64 MB: packed z = W1*h0 + b1 (exchange)

  pack_weights_kernel<<<1024, 256, 0, stream>>>(L0[0], L0[1], L0[2], L0[3], L0[4], L0[5], L0[6], L0[7],
                                                MwT0, MuT0, bias0);
  pack_weights_kernel<<<1024, 256, 0, stream>>>(L1[0], L1[1], L1[2], L1[3], L1[4], L1[5], L1[6], L1[7],
                                                MwT1, MuT1, bias1);
  pack_x_kernel<<<16384, 256, 0, stream>>>(x, Apk);
  // layer-0 input projection (big parallel GEMM)
  gemm_split_kernel<<<dim3(256, 4), 256, 0, stream>>>(Apk, MwT0, bias0, wx);
  // poison all three exchange buffers, then run the 3-stage fused scan
  hipMemsetAsync(Apk, 0xFF, 64 * MB, stream);            // h0 packed exchange
  hipMemsetAsync(d_out, 0xFF, 64 * MB, stream);          // h1 float exchange == output
  hipMemsetAsync(zbuf, 0xFF, 64 * MB, stream);           // z packed exchange
  fused_scan_kernel<<<24, 256, 0, stream>>>(MuT0, wx, MwT1, MuT1, bias1, Apk, (uint*)d_out, zbuf);
}